// Round 1
// baseline (336.146 us; speedup 1.0000x reference)
//
#include <hip/hip_runtime.h>
#include <hip/hip_bf16.h>
#include <hip/hip_fp16.h>

#define H 128           // H_IN == H_OUT == 128
#define BW 128          // nodes per coarse bucket
#define BSH 7           // log2(BW)
#define NB 256          // partition blocks for counting sort

typedef __attribute__((ext_vector_type(8))) short short8;
typedef __attribute__((ext_vector_type(4))) float f32x4;

__device__ inline unsigned short f2bf(float f) {
    union { float f; unsigned int u; } v; v.f = f;
    unsigned int r = (v.u + 0x7fffu + ((v.u >> 16) & 1u)) >> 16;
    return (unsigned short)r;
}
__device__ inline float bf2f(unsigned short h) {
    union { unsigned int u; float f; } v; v.u = ((unsigned int)h) << 16;
    return v.f;
}

// ---------------------------------------------------------------------------
// P1: per-block LDS histogram of dst>>BSH over this block's edge chunk
__global__ __launch_bounds__(256) void p1_hist(const int* __restrict__ ei,
                                               int* __restrict__ counts,
                                               int E, int nbu, int chunk) {
    __shared__ int h[1024];
    for (int i = threadIdx.x; i < nbu; i += 256) h[i] = 0;
    __syncthreads();
    const int b = blockIdx.x;
    const int lo = b * chunk;
    const int hi = min(E, lo + chunk);
    for (int e = lo + threadIdx.x; e < hi; e += 256)
        atomicAdd(&h[ei[E + e] >> BSH], 1);
    __syncthreads();
    for (int i = threadIdx.x; i < nbu; i += 256) counts[b * nbu + i] = h[i];
}

// P2: per bucket, exclusive scan of its NB block-counts
__global__ __launch_bounds__(NB) void p2_scan(const int* __restrict__ counts,
                                              int* __restrict__ scanned,
                                              int* __restrict__ btot, int nbu) {
    __shared__ int s[NB];
    const int k = blockIdx.x, t = threadIdx.x;
    int v = counts[t * nbu + k];
    s[t] = v;
    __syncthreads();
    for (int off = 1; off < NB; off <<= 1) {
        int a = (t >= off) ? s[t - off] : 0;
        __syncthreads();
        s[t] += a;
        __syncthreads();
    }
    scanned[t * nbu + k] = s[t] - v;
    if (t == NB - 1) btot[k] = s[t];
}

// P5: scatter packed edges into exact slots (no global atomics).
// Each block redundantly scans btot -> cstart in LDS (replaces old p3 kernel);
// block 0 also writes the global cstart for csrA/csrB.
__global__ __launch_bounds__(256) void p5_scatter(const int* __restrict__ ei,
                                                  const int* __restrict__ btot,
                                                  const int* __restrict__ scanned,
                                                  int* __restrict__ tmp,
                                                  int* __restrict__ cstart,
                                                  int E, int nbu, int chunk) {
    __shared__ int sc[1024];
    __shared__ int part[256];
    __shared__ int lb[1024];
    const int t = threadIdx.x;
    const int b = blockIdx.x;
    // serial 4-wide load + local inclusive sums
    const int base = t * 4;
    int v0 = (base + 0 < nbu) ? btot[base + 0] : 0;
    int v1 = (base + 1 < nbu) ? btot[base + 1] : 0;
    int v2 = (base + 2 < nbu) ? btot[base + 2] : 0;
    int v3 = (base + 3 < nbu) ? btot[base + 3] : 0;
    int s1 = v0 + v1, s2 = s1 + v2, s3 = s2 + v3;
    part[t] = s3;
    __syncthreads();
    for (int off = 1; off < 256; off <<= 1) {
        int a = (t >= off) ? part[t - off] : 0;
        __syncthreads();
        part[t] += a;
        __syncthreads();
    }
    int add = (t > 0) ? part[t - 1] : 0;
    sc[base + 0] = add;
    sc[base + 1] = add + v0;
    sc[base + 2] = add + s1;
    sc[base + 3] = add + s2;
    __syncthreads();
    if (b == 0) {
        for (int k = t; k < nbu; k += 256) cstart[k] = sc[k];
        if (t == 0) cstart[nbu] = E;
    }
    for (int k = t; k < nbu; k += 256) lb[k] = sc[k] + scanned[b * nbu + k];
    __syncthreads();
    const int lo = b * chunk;
    const int hi = min(E, lo + chunk);
    for (int e = lo + t; e < hi; e += 256) {
        int s = ei[e], d = ei[E + e];
        int slot = atomicAdd(&lb[d >> BSH], 1);
        tmp[slot] = ((d & (BW - 1)) << 17) | s;
    }
}

// csrA: per bucket, local histogram + parallel scan -> rstart, dinv, ainv, selfw
__global__ __launch_bounds__(256) void csra_kernel(const int* __restrict__ tmp,
                                                   const int* __restrict__ cstart,
                                                   const float* __restrict__ invs,
                                                   int* __restrict__ rstart,
                                                   float* __restrict__ dinv,
                                                   float* __restrict__ ainv,
                                                   float* __restrict__ selfw,
                                                   int N, int E) {
    __shared__ int ldeg[BW];
    __shared__ int lscan[BW];   // inclusive scan
    const int b = blockIdx.x;
    const int nstart = b << BSH;
    const int estart = cstart[b];
    const int eend = cstart[b + 1];
    const int t = threadIdx.x;

    if (t < BW) ldeg[t] = 0;
    __syncthreads();
    for (int i = estart + t; i < eend; i += 256)
        atomicAdd(&ldeg[(tmp[i] >> 17) & (BW - 1)], 1);
    __syncthreads();
    if (t < BW) lscan[t] = ldeg[t];
    __syncthreads();
    #pragma unroll
    for (int off = 1; off < BW; off <<= 1) {
        int a = 0;
        if (t < BW && t >= off) a = lscan[t - off];
        __syncthreads();
        if (t < BW) lscan[t] += a;
        __syncthreads();
    }
    if (t < BW) {
        int excl = lscan[t] - ldeg[t];
        int n = nstart + t;
        if (n < N) {
            float iv = invs[n];
            float dv = rsqrtf((float)ldeg[t] + 2.0f);
            rstart[n] = estart + excl;
            dinv[n] = dv;
            ainv[n] = dv * iv;
            selfw[n] = 2.0f * dv * dv * iv;   // self-loop weight incl dequant scale
        }
    }
    if (b == 0 && t == 0) rstart[N] = E;
}

// csrB: scatter src + precomputed f16 edge weight into final CSR slots.
// w_e = ainv[src] * dinv[dst]; ainv for ALL nodes is ready (csrA completed).
__global__ __launch_bounds__(256) void csrb_kernel(const int* __restrict__ tmp,
                                                   const int* __restrict__ cstart,
                                                   const int* __restrict__ rstart,
                                                   const float* __restrict__ dinv,
                                                   const float* __restrict__ ainv,
                                                   int* __restrict__ entries,
                                                   unsigned short* __restrict__ wgt,
                                                   int N, int E) {
    __shared__ int lcur[BW];
    __shared__ float ldv[BW];
    const int b = blockIdx.x;
    const int nstart = b << BSH;
    const int t = threadIdx.x;
    if (t < BW) {
        int n = nstart + t;
        lcur[t] = (n < N) ? rstart[n] : 0;
        ldv[t] = (n < N) ? dinv[n] : 0.f;
    }
    __syncthreads();
    const int estart = cstart[b];
    const int eend = cstart[b + 1];
    for (int i = estart + t; i < eend; i += 256) {
        int v = tmp[i];
        int ld = (v >> 17) & (BW - 1);
        int src = v & 0x1FFFF;
        float w = ainv[src] * ldv[ld];
        int slot = atomicAdd(&lcur[ld], 1);
        entries[slot] = src;
        wgt[slot] = __half_as_ushort(__float2half(w));
    }
}

// ---------------------------------------------------------------------------
// Per-row u8 quantization: 32 lanes per node, lane holds 4 features.
// q = round(x * 127/rowmax) + 128 ; invs = rowmax/127
// Blocks 0..7 additionally pack the W matrices (fused former wpack kernel):
//   mat 0: Wc_hi   mat 1: Ws_hi   mat 2: Ws_lo
__global__ __launch_bounds__(256) void quant_kernel(const float* __restrict__ x,
                                                    const float* __restrict__ Wc,
                                                    const float* __restrict__ Ws,
                                                    uint* __restrict__ xq,
                                                    float* __restrict__ invs,
                                                    short8* __restrict__ wp, int N) {
    int node = blockIdx.x * 8 + (threadIdx.x >> 5);
    if (node < N) {
        int l32 = threadIdx.x & 31;
        float4 v = ((const float4*)x)[node * 32 + l32];
        float m = fmaxf(fmaxf(fabsf(v.x), fabsf(v.y)), fmaxf(fabsf(v.z), fabsf(v.w)));
        #pragma unroll
        for (int mk = 1; mk < 32; mk <<= 1) m = fmaxf(m, __shfl_xor(m, mk));
        m = fmaxf(m, 1e-30f);
        float s = 127.0f / m;
        int q0 = min(255, max(0, (int)rintf(v.x * s) + 128));
        int q1 = min(255, max(0, (int)rintf(v.y * s) + 128));
        int q2 = min(255, max(0, (int)rintf(v.z * s) + 128));
        int q3 = min(255, max(0, (int)rintf(v.w * s) + 128));
        xq[node * 32 + l32] = (uint)q0 | ((uint)q1 << 8) | ((uint)q2 << 16) | ((uint)q3 << 24);
        if (l32 == 0) invs[node] = m / 127.0f;
    }
    if (blockIdx.x < 8) {
        int t = blockIdx.x * 256 + threadIdx.x;   // 0..2047
        int lane = t & 63;
        int nt = (t >> 6) & 7;
        int ks = t >> 9;
        int kbase = ks * 32 + (lane >> 4) * 8;
        int col = nt * 16 + (lane & 15);
        short8 whc, whs, wls;
        #pragma unroll
        for (int j = 0; j < 8; ++j) {
            float wc = Wc[(kbase + j) * H + col];
            float ws = Ws[(kbase + j) * H + col];
            unsigned short hc = f2bf(wc);
            unsigned short hs = f2bf(ws);
            whc[j] = (short)hc;
            whs[j] = (short)hs;
            wls[j] = (short)f2bf(ws - bf2f(hs));
        }
        int base = (ks * 8 + nt) * 64 + lane;
        wp[base] = whc;
        wp[2048 + base] = whs;
        wp[4096 + base] = wls;
    }
}

// ---------------------------------------------------------------------------
// Gather aggregation on u8 x. One wave per node; EIGHTH-wave (8 lanes x
// uint4 = 16 features each) per edge -> 8 edges per iteration. Edge weights
// are precomputed (f16) so the chain is rstart -> {entries,wgt} -> shfl -> xq.
// z[f] = sum_e w_e*q_e[f] - 128*(sum_e w_e + w_self) + w_self*q_self[f]
__global__ __launch_bounds__(256) void agg_kernel(const int* __restrict__ entries,
                                                  const unsigned short* __restrict__ wgt,
                                                  const int* __restrict__ rstart,
                                                  const float* __restrict__ selfw,
                                                  const uint* __restrict__ xq,
                                                  unsigned short* __restrict__ z, int N) {
    int node = blockIdx.x * 4 + (threadIdx.x >> 6);
    if (node >= N) return;
    const int lane = threadIdx.x & 63;
    const int l8 = lane & 7;
    const int g = lane >> 3;
    const uint4* x4 = (const uint4*)xq;   // 16 features per element, 8 per row

    // independent early loads: overlap with the edge chain
    int start = rstart[node];
    int end = rstart[node + 1];
    float sw = selfw[node];
    uint4 qs = x4[node * 8 + l8];

    float acc[16];
    #pragma unroll
    for (int j = 0; j < 16; ++j) acc[j] = 0.f;
    float sumw = 0.f;

    for (int c = start; c < end; c += 64) {
        int rem = end - c;
        int src = 0;
        float w = 0.f;
        if (lane < rem) {
            src = entries[c + lane];
            w = __half2float(__ushort_as_half(wgt[c + lane]));
        }
        int cnt = rem < 64 ? rem : 64;
        int iters = (cnt + 7) >> 3;
        #pragma unroll 4
        for (int t = 0; t < iters; ++t) {
            int idx = 8 * t + g;
            int ss = __shfl(src, idx);
            float wv = __shfl(w, idx);     // 0 when idx >= cnt
            uint4 q = x4[ss * 8 + l8];
            sumw += wv;
            acc[0]  += wv * (float)(q.x & 0xffu);
            acc[1]  += wv * (float)((q.x >> 8) & 0xffu);
            acc[2]  += wv * (float)((q.x >> 16) & 0xffu);
            acc[3]  += wv * (float)(q.x >> 24);
            acc[4]  += wv * (float)(q.y & 0xffu);
            acc[5]  += wv * (float)((q.y >> 8) & 0xffu);
            acc[6]  += wv * (float)((q.y >> 16) & 0xffu);
            acc[7]  += wv * (float)(q.y >> 24);
            acc[8]  += wv * (float)(q.z & 0xffu);
            acc[9]  += wv * (float)((q.z >> 8) & 0xffu);
            acc[10] += wv * (float)((q.z >> 16) & 0xffu);
            acc[11] += wv * (float)(q.z >> 24);
            acc[12] += wv * (float)(q.w & 0xffu);
            acc[13] += wv * (float)((q.w >> 8) & 0xffu);
            acc[14] += wv * (float)((q.w >> 16) & 0xffu);
            acc[15] += wv * (float)(q.w >> 24);
        }
    }

    // reduce over the 8 edge-groups: xor8 on 16 accs, compress halves, xor16/32 on 8
    #pragma unroll
    for (int j = 0; j < 16; ++j) acc[j] += __shfl_xor(acc[j], 8);
    const int hi = g & 1;
    float r[8];
    #pragma unroll
    for (int j = 0; j < 8; ++j) r[j] = hi ? acc[j + 8] : acc[j];
    #pragma unroll
    for (int j = 0; j < 8; ++j) {
        r[j] += __shfl_xor(r[j], 16);
        r[j] += __shfl_xor(r[j], 32);
    }
    sumw += __shfl_xor(sumw, 8);
    sumw += __shfl_xor(sumw, 16);
    sumw += __shfl_xor(sumw, 32);

    if (lane < 16) {
        // lane (l8, hi) owns features [16*l8 + 8*hi, +8); add self contribution once
        uint qa = hi ? qs.z : qs.x;
        uint qb = hi ? qs.w : qs.y;
        r[0] += sw * (float)(qa & 0xffu);
        r[1] += sw * (float)((qa >> 8) & 0xffu);
        r[2] += sw * (float)((qa >> 16) & 0xffu);
        r[3] += sw * (float)(qa >> 24);
        r[4] += sw * (float)(qb & 0xffu);
        r[5] += sw * (float)((qb >> 8) & 0xffu);
        r[6] += sw * (float)((qb >> 16) & 0xffu);
        r[7] += sw * (float)(qb >> 24);
        float off = 128.f * (sumw + sw);
        uint4 o;
        o.x = (uint)f2bf(r[0] - off) | ((uint)f2bf(r[1] - off) << 16);
        o.y = (uint)f2bf(r[2] - off) | ((uint)f2bf(r[3] - off) << 16);
        o.z = (uint)f2bf(r[4] - off) | ((uint)f2bf(r[5] - off) << 16);
        o.w = (uint)f2bf(r[6] - off) | ((uint)f2bf(r[7] - off) << 16);
        ((uint4*)z)[node * 16 + 2 * l8 + (lane >> 3)] = o;
    }
}

// ---------------------------------------------------------------------------
// MFMA GEMM: out = ELU( z@Wc + x@Ws + bc + bsk ), split-bf16 on the x path.
__global__ __launch_bounds__(256) void gemm_kernel(const unsigned short* __restrict__ zb,
                                                   const float* __restrict__ x,
                                                   const short8* __restrict__ wp,
                                                   const float* __restrict__ bc,
                                                   const float* __restrict__ bsk,
                                                   float* __restrict__ out, int N) {
    const int lane = threadIdx.x & 63;
    const int wave = threadIdx.x >> 6;
    const int m = lane & 15;
    const int quad = lane >> 4;
    const int row = blockIdx.x * 64 + wave * 16 + m;
    const bool rowok = row < N;

    f32x4 acc[8];
    #pragma unroll
    for (int i = 0; i < 8; ++i) acc[i] = (f32x4){0.f, 0.f, 0.f, 0.f};

    #pragma unroll
    for (int ks = 0; ks < 4; ++ks) {
        const int k0 = ks * 32 + quad * 8;
        short8 za = {0, 0, 0, 0, 0, 0, 0, 0};
        short8 xa_h = {0, 0, 0, 0, 0, 0, 0, 0};
        short8 xa_l = {0, 0, 0, 0, 0, 0, 0, 0};
        if (rowok) {
            za = ((const short8*)zb)[(row * H + k0) >> 3];
            float4 a = *(const float4*)&x[row * H + k0];
            float4 b = *(const float4*)&x[row * H + k0 + 4];
            float xv[8] = {a.x, a.y, a.z, a.w, b.x, b.y, b.z, b.w};
            #pragma unroll
            for (int j = 0; j < 8; ++j) {
                unsigned short h = f2bf(xv[j]);
                xa_h[j] = (short)h;
                xa_l[j] = (short)f2bf(xv[j] - bf2f(h));
            }
        }
        #pragma unroll
        for (int nt = 0; nt < 8; ++nt) {
            int base = (ks * 8 + nt) * 64 + lane;
            short8 bch = wp[base];
            short8 bsh = wp[2048 + base];
            short8 bsl = wp[4096 + base];
            acc[nt] = __builtin_amdgcn_mfma_f32_16x16x32_bf16(za, bch, acc[nt], 0, 0, 0);
            acc[nt] = __builtin_amdgcn_mfma_f32_16x16x32_bf16(xa_h, bsh, acc[nt], 0, 0, 0);
            acc[nt] = __builtin_amdgcn_mfma_f32_16x16x32_bf16(xa_l, bsh, acc[nt], 0, 0, 0);
            acc[nt] = __builtin_amdgcn_mfma_f32_16x16x32_bf16(xa_h, bsl, acc[nt], 0, 0, 0);
        }
    }

    const int orow_base = blockIdx.x * 64 + wave * 16 + quad * 4;
    #pragma unroll
    for (int nt = 0; nt < 8; ++nt) {
        int col = nt * 16 + m;
        float bias = bc[col] + bsk[col];
        #pragma unroll
        for (int r = 0; r < 4; ++r) {
            int orow = orow_base + r;
            if (orow < N) {
                float v = acc[nt][r] + bias;
                v = v > 0.f ? v : 0.1f * (__expf(v) - 1.f);
                out[orow * H + col] = v;
            }
        }
    }
}

// ---------------------------------------------------------------------------
extern "C" void kernel_launch(void* const* d_in, const int* in_sizes, int n_in,
                              void* d_out, int out_size, void* d_ws, size_t ws_size,
                              hipStream_t stream) {
    const float* x   = (const float*)d_in[0];
    const int*   ei  = (const int*)d_in[1];
    const float* Wc  = (const float*)d_in[2];
    const float* bc  = (const float*)d_in[3];
    const float* Wsk = (const float*)d_in[4];
    const float* bsk = (const float*)d_in[5];
    float* out = (float*)d_out;

    const int N = in_sizes[0] / H;       // 100000
    const int E = in_sizes[1] / 2;       // 1600000
    const int nbu = (N + BW - 1) / BW;   // 782 coarse buckets (<=1024)
    const int chunk = (E + NB - 1) / NB; // 6250 edges per partition block

    // workspace layout (byte offsets), total 49,192,960 B:
    //   0          wp (96KB)
    //   131072     rstart (N+1 ints)
    //   589824     selfw (N f32)
    //   1048576    entries (E ints, 6.4MB)
    //   7471104    wgt (E f16, 3.2MB)
    //   10747904   xq (u8 N*H, 12.8MB)
    //   23592960   z (bf16 N*H, 25.6MB)  -- written only by agg; temporaries
    //              below overlay its region and are all dead before agg:
    //   23592960   invs (N f32)        [quant -> csrA]
    //   23992960   dinv (N f32)        [csrA -> csrB]
    //   24392960   ainv (N f32)        [csrA -> csrB]
    //   24792960   cstart (nbu+1)      [p5 -> csrB]
    //   24796160   btot (nbu)          [p2 -> p5]
    //   24799360   counts (NB*nbu)     [p1 -> p2]
    //   25600128   scanned (NB*nbu)    [p2 -> p5]
    //   26400896   tmp (E ints, 6.4MB) [p5 -> csrB]
    char* w = (char*)d_ws;
    short8*         wp      = (short8*)w;
    int*            rstart  = (int*)(w + 131072);
    float*          selfw   = (float*)(w + 589824);
    int*            entries = (int*)(w + 1048576);
    unsigned short* wgt     = (unsigned short*)(w + 7471104);
    uint*           xq      = (uint*)(w + 10747904);
    unsigned short* z       = (unsigned short*)(w + 23592960);
    float*          invs    = (float*)(w + 23592960);
    float*          dinv    = (float*)(w + 23992960);
    float*          ainv    = (float*)(w + 24392960);
    int*            cstart  = (int*)(w + 24792960);
    int*            btot    = (int*)(w + 24796160);
    int*            counts  = (int*)(w + 24799360);
    int*            scanned = (int*)(w + 25600128);
    int*            tmp     = (int*)(w + 26400896);

    // quant (+ fused W-pack in blocks 0..7)
    quant_kernel<<<(N + 7) / 8, 256, 0, stream>>>(x, Wc, Wsk, xq, invs, wp, N);

    p1_hist<<<NB, 256, 0, stream>>>(ei, counts, E, nbu, chunk);
    p2_scan<<<nbu, NB, 0, stream>>>(counts, scanned, btot, nbu);
    p5_scatter<<<NB, 256, 0, stream>>>(ei, btot, scanned, tmp, cstart, E, nbu, chunk);
    csra_kernel<<<nbu, 256, 0, stream>>>(tmp, cstart, invs, rstart, dinv, ainv, selfw, N, E);
    csrb_kernel<<<nbu, 256, 0, stream>>>(tmp, cstart, rstart, dinv, ainv, entries, wgt, N, E);

    // z = sum(w * q[src]) - 128*sumw + selfloop (bf16)
    agg_kernel<<<(N + 3) / 4, 256, 0, stream>>>(entries, wgt, rstart, selfw, xq, z, N);

    // out = ELU(z@Wc + x@Ws + biases)
    gemm_kernel<<<(N + 63) / 64, 256, 0, stream>>>(z, x, wp, bc, bsk, out, N);
}

// Round 2
// 283.581 us; speedup vs baseline: 1.1854x; 1.1854x over previous
//
#include <hip/hip_runtime.h>
#include <hip/hip_bf16.h>
#include <hip/hip_fp16.h>

#define H 128           // H_IN == H_OUT == 128
#define BW 128          // nodes per coarse bucket
#define BSH 7           // log2(BW)
#define NB 256          // partition blocks for counting sort

typedef __attribute__((ext_vector_type(8))) short short8;
typedef __attribute__((ext_vector_type(4))) float f32x4;

__device__ inline unsigned short f2bf(float f) {
    union { float f; unsigned int u; } v; v.f = f;
    unsigned int r = (v.u + 0x7fffu + ((v.u >> 16) & 1u)) >> 16;
    return (unsigned short)r;
}
__device__ inline float bf2f(unsigned short h) {
    union { unsigned int u; float f; } v; v.u = ((unsigned int)h) << 16;
    return v.f;
}

// ---------------------------------------------------------------------------
// P1: per-block LDS histogram of dst>>BSH over this block's edge chunk
__global__ __launch_bounds__(256) void p1_hist(const int* __restrict__ ei,
                                               int* __restrict__ counts,
                                               int E, int nbu, int chunk) {
    __shared__ int h[1024];
    for (int i = threadIdx.x; i < nbu; i += 256) h[i] = 0;
    __syncthreads();
    const int b = blockIdx.x;
    const int lo = b * chunk;
    const int hi = min(E, lo + chunk);
    for (int e = lo + threadIdx.x; e < hi; e += 256)
        atomicAdd(&h[ei[E + e] >> BSH], 1);
    __syncthreads();
    for (int i = threadIdx.x; i < nbu; i += 256) counts[b * nbu + i] = h[i];
}

// P2: per bucket, exclusive scan of its NB block-counts
__global__ __launch_bounds__(NB) void p2_scan(const int* __restrict__ counts,
                                              int* __restrict__ scanned,
                                              int* __restrict__ btot, int nbu) {
    __shared__ int s[NB];
    const int k = blockIdx.x, t = threadIdx.x;
    int v = counts[t * nbu + k];
    s[t] = v;
    __syncthreads();
    for (int off = 1; off < NB; off <<= 1) {
        int a = (t >= off) ? s[t - off] : 0;
        __syncthreads();
        s[t] += a;
        __syncthreads();
    }
    scanned[t * nbu + k] = s[t] - v;
    if (t == NB - 1) btot[k] = s[t];
}

// P5: scatter packed edges into exact slots (no global atomics).
// Each block redundantly scans btot -> cstart in LDS; block 0 also writes
// the global cstart for csrA/csrB.
__global__ __launch_bounds__(256) void p5_scatter(const int* __restrict__ ei,
                                                  const int* __restrict__ btot,
                                                  const int* __restrict__ scanned,
                                                  int* __restrict__ tmp,
                                                  int* __restrict__ cstart,
                                                  int E, int nbu, int chunk) {
    __shared__ int sc[1024];
    __shared__ int part[256];
    __shared__ int lb[1024];
    const int t = threadIdx.x;
    const int b = blockIdx.x;
    const int base = t * 4;
    int v0 = (base + 0 < nbu) ? btot[base + 0] : 0;
    int v1 = (base + 1 < nbu) ? btot[base + 1] : 0;
    int v2 = (base + 2 < nbu) ? btot[base + 2] : 0;
    int v3 = (base + 3 < nbu) ? btot[base + 3] : 0;
    int s1 = v0 + v1, s2 = s1 + v2, s3 = s2 + v3;
    part[t] = s3;
    __syncthreads();
    for (int off = 1; off < 256; off <<= 1) {
        int a = (t >= off) ? part[t - off] : 0;
        __syncthreads();
        part[t] += a;
        __syncthreads();
    }
    int add = (t > 0) ? part[t - 1] : 0;
    sc[base + 0] = add;
    sc[base + 1] = add + v0;
    sc[base + 2] = add + s1;
    sc[base + 3] = add + s2;
    __syncthreads();
    if (b == 0) {
        for (int k = t; k < nbu; k += 256) cstart[k] = sc[k];
        if (t == 0) cstart[nbu] = E;
    }
    for (int k = t; k < nbu; k += 256) lb[k] = sc[k] + scanned[b * nbu + k];
    __syncthreads();
    const int lo = b * chunk;
    const int hi = min(E, lo + chunk);
    for (int e = lo + t; e < hi; e += 256) {
        int s = ei[e], d = ei[E + e];
        int slot = atomicAdd(&lb[d >> BSH], 1);
        tmp[slot] = ((d & (BW - 1)) << 17) | s;
    }
}

// csrA: per bucket, local histogram + parallel scan -> rstart, dinv, ainv, selfw
__global__ __launch_bounds__(256) void csra_kernel(const int* __restrict__ tmp,
                                                   const int* __restrict__ cstart,
                                                   const float* __restrict__ invs,
                                                   int* __restrict__ rstart,
                                                   float* __restrict__ dinv,
                                                   float* __restrict__ ainv,
                                                   float* __restrict__ selfw,
                                                   int N, int E) {
    __shared__ int ldeg[BW];
    __shared__ int lscan[BW];   // inclusive scan
    const int b = blockIdx.x;
    const int nstart = b << BSH;
    const int estart = cstart[b];
    const int eend = cstart[b + 1];
    const int t = threadIdx.x;

    if (t < BW) ldeg[t] = 0;
    __syncthreads();
    for (int i = estart + t; i < eend; i += 256)
        atomicAdd(&ldeg[(tmp[i] >> 17) & (BW - 1)], 1);
    __syncthreads();
    if (t < BW) lscan[t] = ldeg[t];
    __syncthreads();
    #pragma unroll
    for (int off = 1; off < BW; off <<= 1) {
        int a = 0;
        if (t < BW && t >= off) a = lscan[t - off];
        __syncthreads();
        if (t < BW) lscan[t] += a;
        __syncthreads();
    }
    if (t < BW) {
        int excl = lscan[t] - ldeg[t];
        int n = nstart + t;
        if (n < N) {
            float iv = invs[n];
            float dv = rsqrtf((float)ldeg[t] + 2.0f);
            rstart[n] = estart + excl;
            dinv[n] = dv;
            ainv[n] = dv * iv;
            selfw[n] = 2.0f * dv * dv * iv;   // self-loop weight incl dequant scale
        }
    }
    if (b == 0 && t == 0) rstart[N] = E;
}

// csrB: scatter src + precomputed f16 edge weight into final CSR slots.
__global__ __launch_bounds__(256) void csrb_kernel(const int* __restrict__ tmp,
                                                   const int* __restrict__ cstart,
                                                   const int* __restrict__ rstart,
                                                   const float* __restrict__ dinv,
                                                   const float* __restrict__ ainv,
                                                   int* __restrict__ entries,
                                                   unsigned short* __restrict__ wgt,
                                                   int N, int E) {
    __shared__ int lcur[BW];
    __shared__ float ldv[BW];
    const int b = blockIdx.x;
    const int nstart = b << BSH;
    const int t = threadIdx.x;
    if (t < BW) {
        int n = nstart + t;
        lcur[t] = (n < N) ? rstart[n] : 0;
        ldv[t] = (n < N) ? dinv[n] : 0.f;
    }
    __syncthreads();
    const int estart = cstart[b];
    const int eend = cstart[b + 1];
    for (int i = estart + t; i < eend; i += 256) {
        int v = tmp[i];
        int ld = (v >> 17) & (BW - 1);
        int src = v & 0x1FFFF;
        float w = ainv[src] * ldv[ld];
        int slot = atomicAdd(&lcur[ld], 1);
        entries[slot] = src;
        wgt[slot] = __half_as_ushort(__float2half(w));
    }
}

// ---------------------------------------------------------------------------
// Per-row u8 quantization (+ fused W-pack in blocks 0..7)
__global__ __launch_bounds__(256) void quant_kernel(const float* __restrict__ x,
                                                    const float* __restrict__ Wc,
                                                    const float* __restrict__ Ws,
                                                    uint* __restrict__ xq,
                                                    float* __restrict__ invs,
                                                    short8* __restrict__ wp, int N) {
    int node = blockIdx.x * 8 + (threadIdx.x >> 5);
    if (node < N) {
        int l32 = threadIdx.x & 31;
        float4 v = ((const float4*)x)[node * 32 + l32];
        float m = fmaxf(fmaxf(fabsf(v.x), fabsf(v.y)), fmaxf(fabsf(v.z), fabsf(v.w)));
        #pragma unroll
        for (int mk = 1; mk < 32; mk <<= 1) m = fmaxf(m, __shfl_xor(m, mk));
        m = fmaxf(m, 1e-30f);
        float s = 127.0f / m;
        int q0 = min(255, max(0, (int)rintf(v.x * s) + 128));
        int q1 = min(255, max(0, (int)rintf(v.y * s) + 128));
        int q2 = min(255, max(0, (int)rintf(v.z * s) + 128));
        int q3 = min(255, max(0, (int)rintf(v.w * s) + 128));
        xq[node * 32 + l32] = (uint)q0 | ((uint)q1 << 8) | ((uint)q2 << 16) | ((uint)q3 << 24);
        if (l32 == 0) invs[node] = m / 127.0f;
    }
    if (blockIdx.x < 8) {
        int t = blockIdx.x * 256 + threadIdx.x;   // 0..2047
        int lane = t & 63;
        int nt = (t >> 6) & 7;
        int ks = t >> 9;
        int kbase = ks * 32 + (lane >> 4) * 8;
        int col = nt * 16 + (lane & 15);
        short8 whc, whs, wls;
        #pragma unroll
        for (int j = 0; j < 8; ++j) {
            float wc = Wc[(kbase + j) * H + col];
            float ws = Ws[(kbase + j) * H + col];
            unsigned short hc = f2bf(wc);
            unsigned short hs = f2bf(ws);
            whc[j] = (short)hc;
            whs[j] = (short)hs;
            wls[j] = (short)f2bf(ws - bf2f(hs));
        }
        int base = (ks * 8 + nt) * 64 + lane;
        wp[base] = whc;
        wp[2048 + base] = whs;
        wp[4096 + base] = wls;
    }
}

// ---------------------------------------------------------------------------
// Gather aggregation on u8 x. One wave per node; EIGHTH-wave (8 lanes x
// uint4 = 16 features each) per edge -> 8 edges per iteration. Accumulators
// are 16 NAMED scalars (SROA-proof: no array, no dynamic index, stays in
// VGPRs -- the round-1 acc[16]+select form got promoted to LDS and died of
// bank conflicts). Full xor-8/16/32 reduce; lanes 0..7 store 32B each.
__global__ __launch_bounds__(256) void agg_kernel(const int* __restrict__ entries,
                                                  const unsigned short* __restrict__ wgt,
                                                  const int* __restrict__ rstart,
                                                  const float* __restrict__ selfw,
                                                  const uint* __restrict__ xq,
                                                  unsigned short* __restrict__ z, int N) {
    int node = blockIdx.x * 4 + (threadIdx.x >> 6);
    if (node >= N) return;
    const int lane = threadIdx.x & 63;
    const int l8 = lane & 7;
    const int g = lane >> 3;
    const uint4* x4 = (const uint4*)xq;   // 16 features per element, 8 per row

    // independent early loads: overlap with the edge chain
    int start = rstart[node];
    int end = rstart[node + 1];
    float sw = selfw[node];
    uint4 qs = x4[node * 8 + l8];

    float a00 = 0.f, a01 = 0.f, a02 = 0.f, a03 = 0.f;
    float a04 = 0.f, a05 = 0.f, a06 = 0.f, a07 = 0.f;
    float a08 = 0.f, a09 = 0.f, a10 = 0.f, a11 = 0.f;
    float a12 = 0.f, a13 = 0.f, a14 = 0.f, a15 = 0.f;
    float sumw = 0.f;

    for (int c = start; c < end; c += 64) {
        int rem = end - c;
        int src = 0;
        float w = 0.f;
        if (lane < rem) {
            src = entries[c + lane];
            w = __half2float(__ushort_as_half(wgt[c + lane]));
        }
        int cnt = rem < 64 ? rem : 64;
        int iters = (cnt + 7) >> 3;
        #pragma unroll 4
        for (int t = 0; t < iters; ++t) {
            int idx = 8 * t + g;
            int ss = __shfl(src, idx);
            float wv = __shfl(w, idx);     // 0 when idx >= cnt
            uint4 q = x4[ss * 8 + l8];
            sumw += wv;
            a00 += wv * (float)(q.x & 0xffu);
            a01 += wv * (float)((q.x >> 8) & 0xffu);
            a02 += wv * (float)((q.x >> 16) & 0xffu);
            a03 += wv * (float)(q.x >> 24);
            a04 += wv * (float)(q.y & 0xffu);
            a05 += wv * (float)((q.y >> 8) & 0xffu);
            a06 += wv * (float)((q.y >> 16) & 0xffu);
            a07 += wv * (float)(q.y >> 24);
            a08 += wv * (float)(q.z & 0xffu);
            a09 += wv * (float)((q.z >> 8) & 0xffu);
            a10 += wv * (float)((q.z >> 16) & 0xffu);
            a11 += wv * (float)(q.z >> 24);
            a12 += wv * (float)(q.w & 0xffu);
            a13 += wv * (float)((q.w >> 8) & 0xffu);
            a14 += wv * (float)((q.w >> 16) & 0xffu);
            a15 += wv * (float)(q.w >> 24);
        }
    }

    // full reduce across the 8 edge-groups: after this every lane with the
    // same l8 holds identical totals for feature slice [16*l8, 16*l8+16)
    #define RED3(A) A += __shfl_xor(A, 8); A += __shfl_xor(A, 16); A += __shfl_xor(A, 32);
    RED3(a00) RED3(a01) RED3(a02) RED3(a03)
    RED3(a04) RED3(a05) RED3(a06) RED3(a07)
    RED3(a08) RED3(a09) RED3(a10) RED3(a11)
    RED3(a12) RED3(a13) RED3(a14) RED3(a15)
    RED3(sumw)
    #undef RED3

    // self contribution (identical across g for a given l8)
    a00 += sw * (float)(qs.x & 0xffu);
    a01 += sw * (float)((qs.x >> 8) & 0xffu);
    a02 += sw * (float)((qs.x >> 16) & 0xffu);
    a03 += sw * (float)(qs.x >> 24);
    a04 += sw * (float)(qs.y & 0xffu);
    a05 += sw * (float)((qs.y >> 8) & 0xffu);
    a06 += sw * (float)((qs.y >> 16) & 0xffu);
    a07 += sw * (float)(qs.y >> 24);
    a08 += sw * (float)(qs.z & 0xffu);
    a09 += sw * (float)((qs.z >> 8) & 0xffu);
    a10 += sw * (float)((qs.z >> 16) & 0xffu);
    a11 += sw * (float)(qs.z >> 24);
    a12 += sw * (float)(qs.w & 0xffu);
    a13 += sw * (float)((qs.w >> 8) & 0xffu);
    a14 += sw * (float)((qs.w >> 16) & 0xffu);
    a15 += sw * (float)(qs.w >> 24);

    float off = 128.f * (sumw + sw);

    if (g == 0) {
        uint4 o0, o1;
        o0.x = (uint)f2bf(a00 - off) | ((uint)f2bf(a01 - off) << 16);
        o0.y = (uint)f2bf(a02 - off) | ((uint)f2bf(a03 - off) << 16);
        o0.z = (uint)f2bf(a04 - off) | ((uint)f2bf(a05 - off) << 16);
        o0.w = (uint)f2bf(a06 - off) | ((uint)f2bf(a07 - off) << 16);
        o1.x = (uint)f2bf(a08 - off) | ((uint)f2bf(a09 - off) << 16);
        o1.y = (uint)f2bf(a10 - off) | ((uint)f2bf(a11 - off) << 16);
        o1.z = (uint)f2bf(a12 - off) | ((uint)f2bf(a13 - off) << 16);
        o1.w = (uint)f2bf(a14 - off) | ((uint)f2bf(a15 - off) << 16);
        ((uint4*)z)[node * 16 + 2 * l8] = o0;
        ((uint4*)z)[node * 16 + 2 * l8 + 1] = o1;
    }
}

// ---------------------------------------------------------------------------
// MFMA GEMM: out = ELU( z@Wc + x@Ws + bc + bsk ), split-bf16 on the x path.
__global__ __launch_bounds__(256) void gemm_kernel(const unsigned short* __restrict__ zb,
                                                   const float* __restrict__ x,
                                                   const short8* __restrict__ wp,
                                                   const float* __restrict__ bc,
                                                   const float* __restrict__ bsk,
                                                   float* __restrict__ out, int N) {
    const int lane = threadIdx.x & 63;
    const int wave = threadIdx.x >> 6;
    const int m = lane & 15;
    const int quad = lane >> 4;
    const int row = blockIdx.x * 64 + wave * 16 + m;
    const bool rowok = row < N;

    f32x4 acc[8];
    #pragma unroll
    for (int i = 0; i < 8; ++i) acc[i] = (f32x4){0.f, 0.f, 0.f, 0.f};

    #pragma unroll
    for (int ks = 0; ks < 4; ++ks) {
        const int k0 = ks * 32 + quad * 8;
        short8 za = {0, 0, 0, 0, 0, 0, 0, 0};
        short8 xa_h = {0, 0, 0, 0, 0, 0, 0, 0};
        short8 xa_l = {0, 0, 0, 0, 0, 0, 0, 0};
        if (rowok) {
            za = ((const short8*)zb)[(row * H + k0) >> 3];
            float4 a = *(const float4*)&x[row * H + k0];
            float4 b = *(const float4*)&x[row * H + k0 + 4];
            float xv[8] = {a.x, a.y, a.z, a.w, b.x, b.y, b.z, b.w};
            #pragma unroll
            for (int j = 0; j < 8; ++j) {
                unsigned short h = f2bf(xv[j]);
                xa_h[j] = (short)h;
                xa_l[j] = (short)f2bf(xv[j] - bf2f(h));
            }
        }
        #pragma unroll
        for (int nt = 0; nt < 8; ++nt) {
            int base = (ks * 8 + nt) * 64 + lane;
            short8 bch = wp[base];
            short8 bsh = wp[2048 + base];
            short8 bsl = wp[4096 + base];
            acc[nt] = __builtin_amdgcn_mfma_f32_16x16x32_bf16(za, bch, acc[nt], 0, 0, 0);
            acc[nt] = __builtin_amdgcn_mfma_f32_16x16x32_bf16(xa_h, bsh, acc[nt], 0, 0, 0);
            acc[nt] = __builtin_amdgcn_mfma_f32_16x16x32_bf16(xa_l, bsh, acc[nt], 0, 0, 0);
            acc[nt] = __builtin_amdgcn_mfma_f32_16x16x32_bf16(xa_h, bsl, acc[nt], 0, 0, 0);
        }
    }

    const int orow_base = blockIdx.x * 64 + wave * 16 + quad * 4;
    #pragma unroll
    for (int nt = 0; nt < 8; ++nt) {
        int col = nt * 16 + m;
        float bias = bc[col] + bsk[col];
        #pragma unroll
        for (int r = 0; r < 4; ++r) {
            int orow = orow_base + r;
            if (orow < N) {
                float v = acc[nt][r] + bias;
                v = v > 0.f ? v : 0.1f * (__expf(v) - 1.f);
                out[orow * H + col] = v;
            }
        }
    }
}

// ---------------------------------------------------------------------------
extern "C" void kernel_launch(void* const* d_in, const int* in_sizes, int n_in,
                              void* d_out, int out_size, void* d_ws, size_t ws_size,
                              hipStream_t stream) {
    const float* x   = (const float*)d_in[0];
    const int*   ei  = (const int*)d_in[1];
    const float* Wc  = (const float*)d_in[2];
    const float* bc  = (const float*)d_in[3];
    const float* Wsk = (const float*)d_in[4];
    const float* bsk = (const float*)d_in[5];
    float* out = (float*)d_out;

    const int N = in_sizes[0] / H;       // 100000
    const int E = in_sizes[1] / 2;       // 1600000
    const int nbu = (N + BW - 1) / BW;   // 782 coarse buckets (<=1024)
    const int chunk = (E + NB - 1) / NB; // 6250 edges per partition block

    // workspace layout (byte offsets):
    //   0          wp (96KB)
    //   131072     rstart (N+1 ints)
    //   589824     selfw (N f32)
    //   1048576    entries (E ints, 6.4MB)
    //   7471104    wgt (E f16, 3.2MB)
    //   10747904   xq (u8 N*H, 12.8MB)
    //   23592960   z (bf16 N*H, 25.6MB)  -- written only by agg; temporaries
    //              below overlay its region and are all dead before agg:
    //   23592960   invs / 23992960 dinv / 24392960 ainv
    //   24792960   cstart / 24796160 btot
    //   24799360   counts / 25600128 scanned
    //   26400896   tmp (E ints, 6.4MB)
    char* w = (char*)d_ws;
    short8*         wp      = (short8*)w;
    int*            rstart  = (int*)(w + 131072);
    float*          selfw   = (float*)(w + 589824);
    int*            entries = (int*)(w + 1048576);
    unsigned short* wgt     = (unsigned short*)(w + 7471104);
    uint*           xq      = (uint*)(w + 10747904);
    unsigned short* z       = (unsigned short*)(w + 23592960);
    float*          invs    = (float*)(w + 23592960);
    float*          dinv    = (float*)(w + 23992960);
    float*          ainv    = (float*)(w + 24392960);
    int*            cstart  = (int*)(w + 24792960);
    int*            btot    = (int*)(w + 24796160);
    int*            counts  = (int*)(w + 24799360);
    int*            scanned = (int*)(w + 25600128);
    int*            tmp     = (int*)(w + 26400896);

    // quant (+ fused W-pack in blocks 0..7)
    quant_kernel<<<(N + 7) / 8, 256, 0, stream>>>(x, Wc, Wsk, xq, invs, wp, N);

    p1_hist<<<NB, 256, 0, stream>>>(ei, counts, E, nbu, chunk);
    p2_scan<<<nbu, NB, 0, stream>>>(counts, scanned, btot, nbu);
    p5_scatter<<<NB, 256, 0, stream>>>(ei, btot, scanned, tmp, cstart, E, nbu, chunk);
    csra_kernel<<<nbu, 256, 0, stream>>>(tmp, cstart, invs, rstart, dinv, ainv, selfw, N, E);
    csrb_kernel<<<nbu, 256, 0, stream>>>(tmp, cstart, rstart, dinv, ainv, entries, wgt, N, E);

    // z = sum(w * q[src]) - 128*sumw + selfloop (bf16)
    agg_kernel<<<(N + 3) / 4, 256, 0, stream>>>(entries, wgt, rstart, selfw, xq, z, N);

    // out = ELU(z@Wc + x@Ws + biases)
    gemm_kernel<<<(N + 63) / 64, 256, 0, stream>>>(z, x, wp, bc, bsk, out, N);
}

// Round 3
// 270.526 us; speedup vs baseline: 1.2426x; 1.0483x over previous
//
#include <hip/hip_runtime.h>
#include <hip/hip_bf16.h>
#include <hip/hip_fp16.h>

#define H 128           // H_IN == H_OUT == 128
#define BW 128          // nodes per coarse bucket
#define BSH 7           // log2(BW)
#define NB 256          // partition blocks for counting sort

typedef __attribute__((ext_vector_type(8))) short short8;
typedef __attribute__((ext_vector_type(4))) float f32x4;

__device__ inline unsigned short f2bf(float f) {
    union { float f; unsigned int u; } v; v.f = f;
    unsigned int r = (v.u + 0x7fffu + ((v.u >> 16) & 1u)) >> 16;
    return (unsigned short)r;
}
__device__ inline float bf2f(unsigned short h) {
    union { unsigned int u; float f; } v; v.u = ((unsigned int)h) << 16;
    return v.f;
}

// ---------------------------------------------------------------------------
// Fused: per-row u8 quantization (blocks 0..qb-1), W-pack (blocks 0..7),
// and the p1 edge histogram (blocks qb..qb+NB-1). The histogram role reads
// only edge data, the quant role only x/W -- disjoint, so they run
// concurrently instead of as two serialized launches.
__global__ __launch_bounds__(256) void quant_hist_kernel(const float* __restrict__ x,
                                                         const float* __restrict__ Wc,
                                                         const float* __restrict__ Ws,
                                                         const int* __restrict__ ei,
                                                         uint* __restrict__ xq,
                                                         float* __restrict__ invs,
                                                         short8* __restrict__ wp,
                                                         int* __restrict__ counts,
                                                         int N, int E, int nbu,
                                                         int chunk, int qb) {
    __shared__ int h[1024];
    if (blockIdx.x >= qb) {
        // ---- p1 histogram role ----
        const int b = blockIdx.x - qb;
        for (int i = threadIdx.x; i < nbu; i += 256) h[i] = 0;
        __syncthreads();
        const int lo = b * chunk;
        const int hi = min(E, lo + chunk);
        for (int e = lo + threadIdx.x; e < hi; e += 256)
            atomicAdd(&h[ei[E + e] >> BSH], 1);
        __syncthreads();
        for (int i = threadIdx.x; i < nbu; i += 256) counts[b * nbu + i] = h[i];
        return;
    }
    // ---- quant role ----
    int node = blockIdx.x * 8 + (threadIdx.x >> 5);
    if (node < N) {
        int l32 = threadIdx.x & 31;
        float4 v = ((const float4*)x)[node * 32 + l32];
        float m = fmaxf(fmaxf(fabsf(v.x), fabsf(v.y)), fmaxf(fabsf(v.z), fabsf(v.w)));
        #pragma unroll
        for (int mk = 1; mk < 32; mk <<= 1) m = fmaxf(m, __shfl_xor(m, mk));
        m = fmaxf(m, 1e-30f);
        float s = 127.0f / m;
        int q0 = min(255, max(0, (int)rintf(v.x * s) + 128));
        int q1 = min(255, max(0, (int)rintf(v.y * s) + 128));
        int q2 = min(255, max(0, (int)rintf(v.z * s) + 128));
        int q3 = min(255, max(0, (int)rintf(v.w * s) + 128));
        xq[node * 32 + l32] = (uint)q0 | ((uint)q1 << 8) | ((uint)q2 << 16) | ((uint)q3 << 24);
        if (l32 == 0) invs[node] = m / 127.0f;
    }
    if (blockIdx.x < 8) {
        // ---- W-pack role ----
        int t = blockIdx.x * 256 + threadIdx.x;   // 0..2047
        int lane = t & 63;
        int nt = (t >> 6) & 7;
        int ks = t >> 9;
        int kbase = ks * 32 + (lane >> 4) * 8;
        int col = nt * 16 + (lane & 15);
        short8 whc, whs, wls;
        #pragma unroll
        for (int j = 0; j < 8; ++j) {
            float wc = Wc[(kbase + j) * H + col];
            float ws = Ws[(kbase + j) * H + col];
            unsigned short hc = f2bf(wc);
            unsigned short hs = f2bf(ws);
            whc[j] = (short)hc;
            whs[j] = (short)hs;
            wls[j] = (short)f2bf(ws - bf2f(hs));
        }
        int base = (ks * 8 + nt) * 64 + lane;
        wp[base] = whc;
        wp[2048 + base] = whs;
        wp[4096 + base] = wls;
    }
}

// P2: per bucket, exclusive scan of its NB block-counts
__global__ __launch_bounds__(NB) void p2_scan(const int* __restrict__ counts,
                                              int* __restrict__ scanned,
                                              int* __restrict__ btot, int nbu) {
    __shared__ int s[NB];
    const int k = blockIdx.x, t = threadIdx.x;
    int v = counts[t * nbu + k];
    s[t] = v;
    __syncthreads();
    for (int off = 1; off < NB; off <<= 1) {
        int a = (t >= off) ? s[t - off] : 0;
        __syncthreads();
        s[t] += a;
        __syncthreads();
    }
    scanned[t * nbu + k] = s[t] - v;
    if (t == NB - 1) btot[k] = s[t];
}

// P5: scatter packed edges into exact slots (no global atomics).
// Each block redundantly scans btot -> cstart in LDS; block 0 also writes
// the global cstart for csrA/csrB.
__global__ __launch_bounds__(256) void p5_scatter(const int* __restrict__ ei,
                                                  const int* __restrict__ btot,
                                                  const int* __restrict__ scanned,
                                                  int* __restrict__ tmp,
                                                  int* __restrict__ cstart,
                                                  int E, int nbu, int chunk) {
    __shared__ int sc[1024];
    __shared__ int part[256];
    __shared__ int lb[1024];
    const int t = threadIdx.x;
    const int b = blockIdx.x;
    const int base = t * 4;
    int v0 = (base + 0 < nbu) ? btot[base + 0] : 0;
    int v1 = (base + 1 < nbu) ? btot[base + 1] : 0;
    int v2 = (base + 2 < nbu) ? btot[base + 2] : 0;
    int v3 = (base + 3 < nbu) ? btot[base + 3] : 0;
    int s1 = v0 + v1, s2 = s1 + v2, s3 = s2 + v3;
    part[t] = s3;
    __syncthreads();
    for (int off = 1; off < 256; off <<= 1) {
        int a = (t >= off) ? part[t - off] : 0;
        __syncthreads();
        part[t] += a;
        __syncthreads();
    }
    int add = (t > 0) ? part[t - 1] : 0;
    sc[base + 0] = add;
    sc[base + 1] = add + v0;
    sc[base + 2] = add + s1;
    sc[base + 3] = add + s2;
    __syncthreads();
    if (b == 0) {
        for (int k = t; k < nbu; k += 256) cstart[k] = sc[k];
        if (t == 0) cstart[nbu] = E;
    }
    for (int k = t; k < nbu; k += 256) lb[k] = sc[k] + scanned[b * nbu + k];
    __syncthreads();
    const int lo = b * chunk;
    const int hi = min(E, lo + chunk);
    for (int e = lo + t; e < hi; e += 256) {
        int s = ei[e], d = ei[E + e];
        int slot = atomicAdd(&lb[d >> BSH], 1);
        tmp[slot] = ((d & (BW - 1)) << 17) | s;
    }
}

// csrA: per bucket, local histogram + parallel scan -> rstart, dinv, ainv, selfw
__global__ __launch_bounds__(256) void csra_kernel(const int* __restrict__ tmp,
                                                   const int* __restrict__ cstart,
                                                   const float* __restrict__ invs,
                                                   int* __restrict__ rstart,
                                                   float* __restrict__ dinv,
                                                   float* __restrict__ ainv,
                                                   float* __restrict__ selfw,
                                                   int N, int E) {
    __shared__ int ldeg[BW];
    __shared__ int lscan[BW];   // inclusive scan
    const int b = blockIdx.x;
    const int nstart = b << BSH;
    const int estart = cstart[b];
    const int eend = cstart[b + 1];
    const int t = threadIdx.x;

    if (t < BW) ldeg[t] = 0;
    __syncthreads();
    for (int i = estart + t; i < eend; i += 256)
        atomicAdd(&ldeg[(tmp[i] >> 17) & (BW - 1)], 1);
    __syncthreads();
    if (t < BW) lscan[t] = ldeg[t];
    __syncthreads();
    #pragma unroll
    for (int off = 1; off < BW; off <<= 1) {
        int a = 0;
        if (t < BW && t >= off) a = lscan[t - off];
        __syncthreads();
        if (t < BW) lscan[t] += a;
        __syncthreads();
    }
    if (t < BW) {
        int excl = lscan[t] - ldeg[t];
        int n = nstart + t;
        if (n < N) {
            float iv = invs[n];
            float dv = rsqrtf((float)ldeg[t] + 2.0f);
            rstart[n] = estart + excl;
            dinv[n] = dv;
            ainv[n] = dv * iv;
            selfw[n] = 2.0f * dv * dv * iv;   // self-loop weight incl dequant scale
        }
    }
    if (b == 0 && t == 0) rstart[N] = E;
}

// csrB: scatter src + precomputed f16 edge weight into final CSR slots.
__global__ __launch_bounds__(256) void csrb_kernel(const int* __restrict__ tmp,
                                                   const int* __restrict__ cstart,
                                                   const int* __restrict__ rstart,
                                                   const float* __restrict__ dinv,
                                                   const float* __restrict__ ainv,
                                                   int* __restrict__ entries,
                                                   unsigned short* __restrict__ wgt,
                                                   int N, int E) {
    __shared__ int lcur[BW];
    __shared__ float ldv[BW];
    const int b = blockIdx.x;
    const int nstart = b << BSH;
    const int t = threadIdx.x;
    if (t < BW) {
        int n = nstart + t;
        lcur[t] = (n < N) ? rstart[n] : 0;
        ldv[t] = (n < N) ? dinv[n] : 0.f;
    }
    __syncthreads();
    const int estart = cstart[b];
    const int eend = cstart[b + 1];
    for (int i = estart + t; i < eend; i += 256) {
        int v = tmp[i];
        int ld = (v >> 17) & (BW - 1);
        int src = v & 0x1FFFF;
        float w = ainv[src] * ldv[ld];
        int slot = atomicAdd(&lcur[ld], 1);
        entries[slot] = src;
        wgt[slot] = __half_as_ushort(__float2half(w));
    }
}

// ---------------------------------------------------------------------------
// Gather aggregation on u8 x. Round-0 geometry (known-good 61us): one wave
// per node, QUARTER-wave (16 lanes x uint2 = 8 features each) per edge ->
// 4 edges per iteration. Per-node overhead is the dominant cost at avg
// degree 16, so keep the reduce at 8 accs x 2 shuffle levels. Weights come
// precomputed (f16) -- the divergent ainv[src] gather stage is gone.
// Accumulators are 8 NAMED scalars (SROA-proof; no dynamic indexing).
__global__ __launch_bounds__(256) void agg_kernel(const int* __restrict__ entries,
                                                  const unsigned short* __restrict__ wgt,
                                                  const int* __restrict__ rstart,
                                                  const float* __restrict__ selfw,
                                                  const uint* __restrict__ xq,
                                                  unsigned short* __restrict__ z, int N) {
    int node = blockIdx.x * 4 + (threadIdx.x >> 6);
    if (node >= N) return;
    const int lane = threadIdx.x & 63;
    const int l16 = lane & 15;
    const int q4 = lane >> 4;
    const uint2* x2 = (const uint2*)xq;   // 8 features per element, 16 per row

    // independent early loads: overlap with the edge chain
    int start = rstart[node];
    int end = rstart[node + 1];
    float sw = selfw[node];
    uint2 qs = x2[node * 16 + l16];

    float a0 = 0.f, a1 = 0.f, a2 = 0.f, a3 = 0.f;
    float a4 = 0.f, a5 = 0.f, a6 = 0.f, a7 = 0.f;
    float sumw = 0.f;

    for (int c = start; c < end; c += 64) {
        int rem = end - c;
        int src = 0;
        float w = 0.f;
        if (lane < rem) {
            src = entries[c + lane];
            w = __half2float(__ushort_as_half(wgt[c + lane]));
        }
        int cnt = rem < 64 ? rem : 64;
        int iters = (cnt + 3) >> 2;
        #pragma unroll 4
        for (int t = 0; t < iters; ++t) {
            int idx = 4 * t + q4;
            int ss = __shfl(src, idx);
            float wv = __shfl(w, idx);     // 0 when idx >= cnt
            uint2 q = x2[ss * 16 + l16];
            sumw += wv;
            a0 += wv * (float)(q.x & 0xffu);
            a1 += wv * (float)((q.x >> 8) & 0xffu);
            a2 += wv * (float)((q.x >> 16) & 0xffu);
            a3 += wv * (float)(q.x >> 24);
            a4 += wv * (float)(q.y & 0xffu);
            a5 += wv * (float)((q.y >> 8) & 0xffu);
            a6 += wv * (float)((q.y >> 16) & 0xffu);
            a7 += wv * (float)(q.y >> 24);
        }
    }

    // combine quarters (all lanes end with totals; lanes 0-15 store)
    #define R2(A) A += __shfl_xor(A, 16); A += __shfl_xor(A, 32);
    R2(a0) R2(a1) R2(a2) R2(a3) R2(a4) R2(a5) R2(a6) R2(a7) R2(sumw)
    #undef R2

    if (q4 == 0) {
        // self-loop from own quantized row
        sumw += sw;
        a0 += sw * (float)(qs.x & 0xffu);
        a1 += sw * (float)((qs.x >> 8) & 0xffu);
        a2 += sw * (float)((qs.x >> 16) & 0xffu);
        a3 += sw * (float)(qs.x >> 24);
        a4 += sw * (float)(qs.y & 0xffu);
        a5 += sw * (float)((qs.y >> 8) & 0xffu);
        a6 += sw * (float)((qs.y >> 16) & 0xffu);
        a7 += sw * (float)(qs.y >> 24);
        float off = 128.f * sumw;
        uint4 o;
        o.x = (uint)f2bf(a0 - off) | ((uint)f2bf(a1 - off) << 16);
        o.y = (uint)f2bf(a2 - off) | ((uint)f2bf(a3 - off) << 16);
        o.z = (uint)f2bf(a4 - off) | ((uint)f2bf(a5 - off) << 16);
        o.w = (uint)f2bf(a6 - off) | ((uint)f2bf(a7 - off) << 16);
        ((uint4*)z)[node * 16 + l16] = o;
    }
}

// ---------------------------------------------------------------------------
// MFMA GEMM: out = ELU( z@Wc + x@Ws + bc + bsk ), split-bf16 on the x path.
__global__ __launch_bounds__(256) void gemm_kernel(const unsigned short* __restrict__ zb,
                                                   const float* __restrict__ x,
                                                   const short8* __restrict__ wp,
                                                   const float* __restrict__ bc,
                                                   const float* __restrict__ bsk,
                                                   float* __restrict__ out, int N) {
    const int lane = threadIdx.x & 63;
    const int wave = threadIdx.x >> 6;
    const int m = lane & 15;
    const int quad = lane >> 4;
    const int row = blockIdx.x * 64 + wave * 16 + m;
    const bool rowok = row < N;

    f32x4 acc[8];
    #pragma unroll
    for (int i = 0; i < 8; ++i) acc[i] = (f32x4){0.f, 0.f, 0.f, 0.f};

    #pragma unroll
    for (int ks = 0; ks < 4; ++ks) {
        const int k0 = ks * 32 + quad * 8;
        short8 za = {0, 0, 0, 0, 0, 0, 0, 0};
        short8 xa_h = {0, 0, 0, 0, 0, 0, 0, 0};
        short8 xa_l = {0, 0, 0, 0, 0, 0, 0, 0};
        if (rowok) {
            za = ((const short8*)zb)[(row * H + k0) >> 3];
            float4 a = *(const float4*)&x[row * H + k0];
            float4 b = *(const float4*)&x[row * H + k0 + 4];
            float xv[8] = {a.x, a.y, a.z, a.w, b.x, b.y, b.z, b.w};
            #pragma unroll
            for (int j = 0; j < 8; ++j) {
                unsigned short h = f2bf(xv[j]);
                xa_h[j] = (short)h;
                xa_l[j] = (short)f2bf(xv[j] - bf2f(h));
            }
        }
        #pragma unroll
        for (int nt = 0; nt < 8; ++nt) {
            int base = (ks * 8 + nt) * 64 + lane;
            short8 bch = wp[base];
            short8 bsh = wp[2048 + base];
            short8 bsl = wp[4096 + base];
            acc[nt] = __builtin_amdgcn_mfma_f32_16x16x32_bf16(za, bch, acc[nt], 0, 0, 0);
            acc[nt] = __builtin_amdgcn_mfma_f32_16x16x32_bf16(xa_h, bsh, acc[nt], 0, 0, 0);
            acc[nt] = __builtin_amdgcn_mfma_f32_16x16x32_bf16(xa_l, bsh, acc[nt], 0, 0, 0);
            acc[nt] = __builtin_amdgcn_mfma_f32_16x16x32_bf16(xa_h, bsl, acc[nt], 0, 0, 0);
        }
    }

    const int orow_base = blockIdx.x * 64 + wave * 16 + quad * 4;
    #pragma unroll
    for (int nt = 0; nt < 8; ++nt) {
        int col = nt * 16 + m;
        float bias = bc[col] + bsk[col];
        #pragma unroll
        for (int r = 0; r < 4; ++r) {
            int orow = orow_base + r;
            if (orow < N) {
                float v = acc[nt][r] + bias;
                v = v > 0.f ? v : 0.1f * (__expf(v) - 1.f);
                out[orow * H + col] = v;
            }
        }
    }
}

// ---------------------------------------------------------------------------
extern "C" void kernel_launch(void* const* d_in, const int* in_sizes, int n_in,
                              void* d_out, int out_size, void* d_ws, size_t ws_size,
                              hipStream_t stream) {
    const float* x   = (const float*)d_in[0];
    const int*   ei  = (const int*)d_in[1];
    const float* Wc  = (const float*)d_in[2];
    const float* bc  = (const float*)d_in[3];
    const float* Wsk = (const float*)d_in[4];
    const float* bsk = (const float*)d_in[5];
    float* out = (float*)d_out;

    const int N = in_sizes[0] / H;       // 100000
    const int E = in_sizes[1] / 2;       // 1600000
    const int nbu = (N + BW - 1) / BW;   // 782 coarse buckets (<=1024)
    const int chunk = (E + NB - 1) / NB; // 6250 edges per partition block
    const int qb = (N + 7) / 8;          // quant blocks

    // workspace layout (byte offsets) -- identical to the proven round-2 map:
    //   0          wp (96KB)
    //   131072     rstart (N+1 ints)
    //   589824     selfw (N f32)
    //   1048576    entries (E ints, 6.4MB)
    //   7471104    wgt (E f16, 3.2MB)
    //   10747904   xq (u8 N*H, 12.8MB)
    //   23592960   z (bf16 N*H, 25.6MB)  -- written only by agg; temporaries
    //              below overlay its region and are all dead before agg:
    //   23592960   invs / 23992960 dinv / 24392960 ainv
    //   24792960   cstart / 24796160 btot
    //   24799360   counts / 25600128 scanned
    //   26400896   tmp (E ints, 6.4MB)
    char* w = (char*)d_ws;
    short8*         wp      = (short8*)w;
    int*            rstart  = (int*)(w + 131072);
    float*          selfw   = (float*)(w + 589824);
    int*            entries = (int*)(w + 1048576);
    unsigned short* wgt     = (unsigned short*)(w + 7471104);
    uint*           xq      = (uint*)(w + 10747904);
    unsigned short* z       = (unsigned short*)(w + 23592960);
    float*          invs    = (float*)(w + 23592960);
    float*          dinv    = (float*)(w + 23992960);
    float*          ainv    = (float*)(w + 24392960);
    int*            cstart  = (int*)(w + 24792960);
    int*            btot    = (int*)(w + 24796160);
    int*            counts  = (int*)(w + 24799360);
    int*            scanned = (int*)(w + 25600128);
    int*            tmp     = (int*)(w + 26400896);

    // quant + W-pack + p1 histogram, fused (histogram blocks appended)
    quant_hist_kernel<<<qb + NB, 256, 0, stream>>>(x, Wc, Wsk, ei, xq, invs, wp,
                                                   counts, N, E, nbu, chunk, qb);

    p2_scan<<<nbu, NB, 0, stream>>>(counts, scanned, btot, nbu);
    p5_scatter<<<NB, 256, 0, stream>>>(ei, btot, scanned, tmp, cstart, E, nbu, chunk);
    csra_kernel<<<nbu, 256, 0, stream>>>(tmp, cstart, invs, rstart, dinv, ainv, selfw, N, E);
    csrb_kernel<<<nbu, 256, 0, stream>>>(tmp, cstart, rstart, dinv, ainv, entries, wgt, N, E);

    // z = sum(w * q[src]) - 128*sumw + selfloop (bf16)
    agg_kernel<<<(N + 3) / 4, 256, 0, stream>>>(entries, wgt, rstart, selfw, xq, z, N);

    // out = ELU(z@Wc + x@Ws + biases)
    gemm_kernel<<<(N + 63) / 64, 256, 0, stream>>>(z, x, wp, bc, bsk, out, N);
}